// Round 19
// baseline (322.986 us; speedup 1.0000x reference)
//
#include <hip/hip_runtime.h>
#include <hip/hip_bf16.h>
#include <stdint.h>

#define NHEADS 16
#define HDIM 80
#define CHUNK 2048
#define QSCALE 0.11180339887498949f   /* 80^-0.5 */
#define L2E 1.4426950408889634f

typedef __bf16 bf16x8 __attribute__((ext_vector_type(8)));
typedef float f32x4 __attribute__((ext_vector_type(4)));

__device__ __forceinline__ unsigned short f2bf(float f) {
  union { float f; unsigned u; } x; x.f = f;
  unsigned r = (x.u + 0x7fffu + ((x.u >> 16) & 1u)) >> 16;
  return (unsigned short)r;
}

__device__ __forceinline__ float fexp2(float x) {   // raw v_exp_f32
  float r;
  asm("v_exp_f32 %0, %1" : "=v"(r) : "v"(x));
  return r;
}

__device__ __forceinline__ unsigned cvtpk(float lo, float hi) {
  unsigned r;
  asm("v_cvt_pk_bf16_f32 %0, %1, %2" : "=v"(r) : "v"(lo), "v"(hi));
  return r;
}

__device__ __forceinline__ void gload16(const void* g, void* lds) {
  __builtin_amdgcn_global_load_lds((const __attribute__((address_space(1))) void*)g,
                                   (__attribute__((address_space(3))) void*)lds, 16, 0, 0);
}

/* ---------------- fused fp32 -> bf16 convert (all three arrays, one launch) ---------------- */
__global__ __launch_bounds__(256) void cvt3_f32_bf16(
    const float* __restrict__ a, unsigned short* __restrict__ ao, int na4,
    const float* __restrict__ b, unsigned short* __restrict__ bo, int nb4,
    const float* __restrict__ c, unsigned short* __restrict__ co, int nc4) {
  const int stride = gridDim.x * 256;
  for (int i = blockIdx.x * 256 + threadIdx.x; i < na4; i += stride) {
    float4 v = reinterpret_cast<const float4*>(a)[i];
    ushort4 o; o.x = f2bf(v.x); o.y = f2bf(v.y); o.z = f2bf(v.z); o.w = f2bf(v.w);
    reinterpret_cast<ushort4*>(ao)[i] = o;
  }
  for (int i = blockIdx.x * 256 + threadIdx.x; i < nb4; i += stride) {
    float4 v = reinterpret_cast<const float4*>(b)[i];
    ushort4 o; o.x = f2bf(v.x); o.y = f2bf(v.y); o.z = f2bf(v.z); o.w = f2bf(v.w);
    reinterpret_cast<ushort4*>(bo)[i] = o;
  }
  for (int i = blockIdx.x * 256 + threadIdx.x; i < nc4; i += stride) {
    float4 v = reinterpret_cast<const float4*>(c)[i];
    ushort4 o; o.x = f2bf(v.x); o.y = f2bf(v.y); o.z = f2bf(v.z); o.w = f2bf(v.w);
    reinterpret_cast<ushort4*>(co)[i] = o;
  }
}

/* ---------------- bf16 GEMM, BK=64, XOR-swizzled LDS (round-13 proven) ----------------
   Fused V-transpose epilogue (round-15 proven). */
__global__ __launch_bounds__(256) void gemm_bt(
    const unsigned short* __restrict__ A, const unsigned short* __restrict__ B,
    const float* __restrict__ bias, unsigned short* __restrict__ C,
    float* __restrict__ Cf, unsigned short* __restrict__ vt,
    int M, int N, int K, int lda, int scaleN, float scaleVal)
{
  __shared__ unsigned short Ash[128 * 64];
  __shared__ unsigned short Bsh[128 * 64];
  const int tid = threadIdx.x;
  const int lane = tid & 63;
  const int w = tid >> 6;
  const int wr = w >> 1, wc = w & 1;
  const int l15 = lane & 15, lq = lane >> 4;
  const long bm = (long)blockIdx.y * 128;
  const long bn = (long)blockIdx.x * 128;

  f32x4 acc[4][4];
#pragma unroll
  for (int i = 0; i < 4; i++)
#pragma unroll
    for (int j = 0; j < 4; j++) acc[i][j] = f32x4{0.f, 0.f, 0.f, 0.f};

  const int rlo = lane >> 3;
  const int sg  = (lane & 7) ^ rlo;

  for (long k0 = 0; k0 < K; k0 += 64) {
    __syncthreads();
#pragma unroll
    for (int j = 0; j < 4; j++) {
      int c = w * 4 + j;
      gload16(A + (bm + c * 8 + rlo) * (long)lda + k0 + sg * 8,
              (char*)Ash + c * 1024);
      gload16(B + (bn + c * 8 + rlo) * (long)K + k0 + sg * 8,
              (char*)Bsh + c * 1024);
    }
    __syncthreads();
#pragma unroll
    for (int kk = 0; kk < 2; kk++) {
      const int so = (((kk * 4 + lq) ^ (l15 & 7))) * 8;
      bf16x8 af[4], bfr[4];
#pragma unroll
      for (int x = 0; x < 4; x++) {
        af[x]  = *reinterpret_cast<const bf16x8*>(Ash + (wr * 64 + x * 16 + l15) * 64 + so);
        bfr[x] = *reinterpret_cast<const bf16x8*>(Bsh + (wc * 64 + x * 16 + l15) * 64 + so);
      }
#pragma unroll
      for (int x = 0; x < 4; x++)
#pragma unroll
        for (int y = 0; y < 4; y++)
          acc[x][y] = __builtin_amdgcn_mfma_f32_16x16x32_bf16(af[x], bfr[y], acc[x][y], 0, 0, 0);
    }
  }

#pragma unroll
  for (int x = 0; x < 4; x++) {
    long row0 = bm + wr * 64 + x * 16 + lq * 4;
#pragma unroll
    for (int y = 0; y < 4; y++) {
      int colu = (int)bn + wc * 64 + y * 16;
      int col = colu + l15;
      float bs = bias[col];
      if (vt != nullptr && colu >= 2560) {
        int vcol = col - 2560;
        int vh = vcol / 80, vd = vcol % 80;
        int chp = ((int)(row0 >> 11)) * 16 + vh;
        int seq = (int)row0 & 2047;
        ushort4 o;
        o.x = f2bf(acc[x][y][0] + bs);
        o.y = f2bf(acc[x][y][1] + bs);
        o.z = f2bf(acc[x][y][2] + bs);
        o.w = f2bf(acc[x][y][3] + bs);
        *reinterpret_cast<ushort4*>(vt + ((size_t)chp * 80 + vd) * 2048 + seq) = o;
      } else {
        float sc = (col < scaleN) ? scaleVal : 1.0f;
        if (Cf != nullptr) {
#pragma unroll
          for (int r = 0; r < 4; r++)
            Cf[(size_t)(row0 + r) * N + col] = (acc[x][y][r] + bs) * sc;
        } else {
#pragma unroll
          for (int r = 0; r < 4; r++)
            C[(size_t)(row0 + r) * N + col] = f2bf((acc[x][y][r] + bs) * sc);
        }
      }
    }
  }
}

/* ---------------- flash attention: swapped-QK^T, P in registers, VALU row-sum ----------------
   Round-18 structure + sum-column MFMA removed: denominator accumulated in
   VALU from the in-register P values (lst[2], s-layout q=l15; alpha-rescale
   is a uniform per-l15 multiply there). Frees acc[.][5] (8 AGPR) + onesb
   (4 VGPR): total regs ~122 <= 128 granule -> target 4 waves/SIMD (2x). */
__global__ __launch_bounds__(256, 3) void attn_kernel(
    const unsigned short* __restrict__ qkv, const unsigned short* __restrict__ vt,
    unsigned short* __restrict__ outq)
{
  __shared__ char Kbuf[10240];                  // K tile [64][80], linear
  __shared__ char Vbuf[12288];                  // V tile [80][72]

  const int tid = threadIdx.x;
  const int lane = tid & 63;
  const int w = tid >> 6;
  const int l15 = lane & 15, lq = lane >> 4;

  // XCD-aware decode
  const int b = blockIdx.x;
  const int qt = (b >> 3) & 15;
  const int chp = (b & 7) * 8 + (b >> 7);
  const int ch = chp >> 4;
  const int head = chp & 15;

  const size_t rs = 3840;
  const unsigned short* qbase = qkv + (size_t)(ch * CHUNK) * rs + head * HDIM;
  const char* kbase = (const char*)(qbase + 1280);
  const char* vbase = (const char*)(vt + (size_t)chp * HDIM * 2048);

  int kgo[3]; bool kact[3];
  const int koff0 = w * 1024;
#pragma unroll
  for (int j = 0; j < 3; j++) {
    int c = w + 4 * j;
    kact[j] = (c < 10);
    int cc = kact[j] ? c : 0;
    int s = cc * 64 + lane;
    kgo[j] = (s / 10) * 7680 + (s % 10) * 16;
  }
  int vgo[3];
  const int vw = (w + 2) & 3;
#pragma unroll
  for (int j = 0; j < 3; j++) {
    int c = vw + 4 * j;
    int s2 = c * 64 + lane;
    if (s2 > 719) s2 = 719;
    int d = s2 / 9, u = s2 % 9;
    int ue = (u == 8) ? 0 : u;
    vgo[j] = d * 4096 + ue * 16;
  }

  // Q fragments
  const int qr0 = qt * 128 + w * 32;
  bf16x8 qa[2][2], qa2[2];
#pragma unroll
  for (int qf = 0; qf < 2; qf++) {
    const unsigned short* qrow = qbase + (size_t)(qr0 + qf * 16 + l15) * rs;
    qa[qf][0] = *reinterpret_cast<const bf16x8*>(qrow + lq * 8);
    qa[qf][1] = *reinterpret_cast<const bf16x8*>(qrow + 32 + lq * 8);
    if (lq < 2) qa2[qf] = *reinterpret_cast<const bf16x8*>(qrow + 64 + lq * 8);
    else        qa2[qf] = bf16x8{};
  }

  f32x4 acc[2][5];
#pragma unroll
  for (int qf = 0; qf < 2; qf++)
#pragma unroll
    for (int df = 0; df < 5; df++) acc[qf][df] = f32x4{0.f, 0.f, 0.f, 0.f};
  float mst[2] = {16.0f, 16.0f};   // per-lane q = l15
  float lst[2] = {0.0f, 0.0f};     // denominator partial (s-layout, per lq-lane)

  // prologue: stage K0, V0
#pragma unroll
  for (int j = 0; j < 3; j++)
    if (kact[j]) gload16(kbase + kgo[j], Kbuf + koff0 + j * 4096);
#pragma unroll
  for (int j = 0; j < 3; j++) gload16(vbase + vgo[j], Vbuf + vw * 1024 + j * 4096);
  __syncthreads();

  for (int kt = 0; kt < CHUNK; kt += 64) {
    // swapped QK^T: lane holds q=l15, k=kf*16+lq*4+r
    float tmax[2] = {-1e30f, -1e30f};
    float psum[2] = {0.0f, 0.0f};
    union { unsigned u[4]; bf16x8 v; } paq[2][2];

    const unsigned short* Ksh = (const unsigned short*)Kbuf;
#pragma unroll
    for (int kf = 0; kf < 4; kf++) {
      const unsigned short* kr = Ksh + (kf * 16 + l15) * 80;
      bf16x8 kb0 = *reinterpret_cast<const bf16x8*>(kr + lq * 8);
      bf16x8 kb1 = *reinterpret_cast<const bf16x8*>(kr + 32 + lq * 8);
      bf16x8 kb2 = (lq < 2) ? *reinterpret_cast<const bf16x8*>(kr + 64 + lq * 8) : bf16x8{};
#pragma unroll
      for (int qf = 0; qf < 2; qf++) {
        f32x4 sv = f32x4{0.f, 0.f, 0.f, 0.f};
        sv = __builtin_amdgcn_mfma_f32_16x16x32_bf16(kb0, qa[qf][0], sv, 0, 0, 0);
        sv = __builtin_amdgcn_mfma_f32_16x16x32_bf16(kb1, qa[qf][1], sv, 0, 0, 0);
        sv = __builtin_amdgcn_mfma_f32_16x16x32_bf16(kb2, qa2[qf], sv, 0, 0, 0);
        tmax[qf] = fmaxf(tmax[qf],
                         fmaxf(fmaxf(sv[0], sv[1]), fmaxf(sv[2], sv[3])));
        float p0 = fexp2((sv[0] - mst[qf]) * L2E);
        float p1 = fexp2((sv[1] - mst[qf]) * L2E);
        float p2 = fexp2((sv[2] - mst[qf]) * L2E);
        float p3 = fexp2((sv[3] - mst[qf]) * L2E);
        psum[qf] += (p0 + p1) + (p2 + p3);
        paq[qf][kf >> 1].u[(kf & 1) * 2]     = cvtpk(p0, p1);
        paq[qf][kf >> 1].u[(kf & 1) * 2 + 1] = cvtpk(p2, p3);
      }
    }

    // denominator: lst_new = alpha*(lst_old + psum)  (alpha applied in resc branch)
    lst[0] += psum[0];
    lst[1] += psum[1];

    // rescale decision (post-PV application for acc)
    const bool resc = __any((tmax[0] > mst[0] + 8.0f) || (tmax[1] > mst[1] + 8.0f));
    float alpha_acc[2][4];
    if (resc) {
#pragma unroll
      for (int qf = 0; qf < 2; qf++) {
        float t = tmax[qf];
        t = fmaxf(t, __shfl_xor(t, 16, 64));
        t = fmaxf(t, __shfl_xor(t, 32, 64));
        float mnew = fmaxf(mst[qf], t);
        float a_s = fexp2((mst[qf] - mnew) * L2E);
        mst[qf] = mnew;
        lst[qf] *= a_s;                      // denominator rescale (s-layout, uniform per l15)
#pragma unroll
        for (int r = 0; r < 4; r++)
          alpha_acc[qf][r] = __shfl(a_s, lq * 4 + r, 64);
      }
    }

    __syncthreads();   // B1: all waves done reading K(t); drains V(t) loads

    // issue K(t+1); hides under PV
    if (kt + 64 < CHUNK) {
      const int ktB = (kt + 64) * 7680;
#pragma unroll
      for (int j = 0; j < 3; j++)
        if (kact[j]) gload16(kbase + kgo[j] + ktB, Kbuf + koff0 + j * 4096);
    }

    // PV; V read with the same k-permutation as paq
    const unsigned short* Vsh = (const unsigned short*)Vbuf;
#pragma unroll
    for (int ks = 0; ks < 2; ks++) {
#pragma unroll
      for (int df = 0; df < 5; df++) {
        const unsigned short* vp = Vsh + (df * 16 + l15) * 72 + ks * 32 + lq * 4;
        union { unsigned u[4]; bf16x8 v; } vb;
        *reinterpret_cast<uint2*>(&vb.u[0]) = *reinterpret_cast<const uint2*>(vp);
        *reinterpret_cast<uint2*>(&vb.u[2]) = *reinterpret_cast<const uint2*>(vp + 16);
#pragma unroll
        for (int qf = 0; qf < 2; qf++)
          acc[qf][df] = __builtin_amdgcn_mfma_f32_16x16x32_bf16(paq[qf][ks].v, vb.v, acc[qf][df], 0, 0, 0);
      }
    }

    // deferred rescale (rare)
    if (resc) {
#pragma unroll
      for (int qf = 0; qf < 2; qf++)
#pragma unroll
        for (int df = 0; df < 5; df++)
#pragma unroll
          for (int r = 0; r < 4; r++) acc[qf][df][r] *= alpha_acc[qf][r];
    }

    __syncthreads();   // B2: all waves done reading V(t); drains K(t+1) loads

    // issue V(t+1); hides under next tile's QK^T + softmax
    if (kt + 64 < CHUNK) {
      const int ktV = (kt + 64) * 2;
#pragma unroll
      for (int j = 0; j < 3; j++)
        gload16(vbase + vgo[j] + ktV, Vbuf + vw * 1024 + j * 4096);
    }
  }

  // epilogue: finish denominator (reduce over lq), exchange to acc-layout, divide
  unsigned short* obase = outq + (size_t)(ch * CHUNK) * rs + head * HDIM;
#pragma unroll
  for (int qf = 0; qf < 2; qf++) {
    float s = lst[qf];
    s += __shfl_xor(s, 16, 64);
    s += __shfl_xor(s, 32, 64);
    float inv_s = 1.0f / s;
    float inv[4];
#pragma unroll
    for (int r = 0; r < 4; r++) inv[r] = __shfl(inv_s, lq * 4 + r, 64);
#pragma unroll
    for (int df = 0; df < 5; df++) {
      int col = df * 16 + l15;
#pragma unroll
      for (int r = 0; r < 4; r++) {
        float v = acc[qf][df][r] * inv[r];
        obase[(size_t)(qr0 + qf * 16 + lq * 4 + r) * rs + col] = f2bf(v);
      }
    }
  }
}

extern "C" void kernel_launch(void* const* d_in, const int* in_sizes, int n_in,
                              void* d_out, int out_size, void* d_ws, size_t ws_size,
                              hipStream_t stream) {
  const float* hs    = (const float*)d_in[0];   // [8192][1280]
  const float* qkvw  = (const float*)d_in[2];   // [3840][1280]
  const float* qkvb  = (const float*)d_in[3];   // [3840]
  const float* projw = (const float*)d_in[4];   // [1280][1280]
  const float* projb = (const float*)d_in[5];   // [1280]

  char* ws = (char*)d_ws;
  unsigned short* hs_bf    = (unsigned short*)ws;                         // 20,971,520 B
  unsigned short* qkvw_bf  = (unsigned short*)(ws + 20971520);            //  9,830,400 B
  unsigned short* projw_bf = (unsigned short*)(ws + 20971520 + 9830400);  //  3,276,800 B
  unsigned short* qkv_bf   = (unsigned short*)(ws + 20971520 + 9830400 + 3276800); // 62,914,560 B
  // vT lives in d_out (41.9 MB fp32 buffer; scratch until proj GEMM overwrites it)
  unsigned short* vT = (unsigned short*)d_out;  // 20,971,520 B needed

  cvt3_f32_bf16<<<2048, 256, 0, stream>>>(hs, hs_bf, 8192 * 1280 / 4,
                                          qkvw, qkvw_bf, 3840 * 1280 / 4,
                                          projw, projw_bf, 1280 * 1280 / 4);

  // qkv = hs @ qkv_w^T + qkv_b ; q cols pre-scaled (bf16 out); V cols -> vT transposed
  gemm_bt<<<dim3(30, 64), 256, 0, stream>>>(hs_bf, qkvw_bf, qkvb, qkv_bf, nullptr, vT,
                                            8192, 3840, 1280, 1280, 1280, QSCALE);
  // attention; output overwrites Q-columns of qkv_bf (XCD-swizzled 1-D grid)
  attn_kernel<<<dim3(1024), 256, 0, stream>>>(qkv_bf, vT, qkv_bf);
  // out = attn @ proj_w^T + proj_b (fp32 out), A has row stride 3840
  gemm_bt<<<dim3(10, 64), 256, 0, stream>>>(qkv_bf, projw_bf, projb,
                                            nullptr, (float*)d_out, nullptr,
                                            8192, 1280, 1280, 3840, 0, 1.0f);
}

// Round 20
// 278.500 us; speedup vs baseline: 1.1597x; 1.1597x over previous
//
#include <hip/hip_runtime.h>
#include <hip/hip_bf16.h>
#include <stdint.h>

#define NHEADS 16
#define HDIM 80
#define CHUNK 2048
#define QSCALE 0.11180339887498949f   /* 80^-0.5 */
#define L2E 1.4426950408889634f

typedef __bf16 bf16x8 __attribute__((ext_vector_type(8)));
typedef float f32x4 __attribute__((ext_vector_type(4)));

__device__ __forceinline__ unsigned short f2bf(float f) {
  union { float f; unsigned u; } x; x.f = f;
  unsigned r = (x.u + 0x7fffu + ((x.u >> 16) & 1u)) >> 16;
  return (unsigned short)r;
}

__device__ __forceinline__ float fexp2(float x) {   // raw v_exp_f32
  float r;
  asm("v_exp_f32 %0, %1" : "=v"(r) : "v"(x));
  return r;
}

__device__ __forceinline__ unsigned cvtpk(float lo, float hi) {
  unsigned r;
  asm("v_cvt_pk_bf16_f32 %0, %1, %2" : "=v"(r) : "v"(lo), "v"(hi));
  return r;
}

__device__ __forceinline__ void gload16(const void* g, void* lds) {
  __builtin_amdgcn_global_load_lds((const __attribute__((address_space(1))) void*)g,
                                   (__attribute__((address_space(3))) void*)lds, 16, 0, 0);
}

/* ---------------- fused fp32 -> bf16 convert (all three arrays, one launch) ---------------- */
__global__ __launch_bounds__(256) void cvt3_f32_bf16(
    const float* __restrict__ a, unsigned short* __restrict__ ao, int na4,
    const float* __restrict__ b, unsigned short* __restrict__ bo, int nb4,
    const float* __restrict__ c, unsigned short* __restrict__ co, int nc4) {
  const int stride = gridDim.x * 256;
  for (int i = blockIdx.x * 256 + threadIdx.x; i < na4; i += stride) {
    float4 v = reinterpret_cast<const float4*>(a)[i];
    ushort4 o; o.x = f2bf(v.x); o.y = f2bf(v.y); o.z = f2bf(v.z); o.w = f2bf(v.w);
    reinterpret_cast<ushort4*>(ao)[i] = o;
  }
  for (int i = blockIdx.x * 256 + threadIdx.x; i < nb4; i += stride) {
    float4 v = reinterpret_cast<const float4*>(b)[i];
    ushort4 o; o.x = f2bf(v.x); o.y = f2bf(v.y); o.z = f2bf(v.z); o.w = f2bf(v.w);
    reinterpret_cast<ushort4*>(bo)[i] = o;
  }
  for (int i = blockIdx.x * 256 + threadIdx.x; i < nc4; i += stride) {
    float4 v = reinterpret_cast<const float4*>(c)[i];
    ushort4 o; o.x = f2bf(v.x); o.y = f2bf(v.y); o.z = f2bf(v.z); o.w = f2bf(v.w);
    reinterpret_cast<ushort4*>(co)[i] = o;
  }
}

/* ---------------- bf16 GEMM, BK=64, XOR-swizzled LDS (round-13 proven) ----------------
   Fused V-transpose epilogue (round-15 proven): when vt != nullptr, columns
   >= 2560 are written TRANSPOSED to vt[chp][80][2048] instead of C. */
__global__ __launch_bounds__(256) void gemm_bt(
    const unsigned short* __restrict__ A, const unsigned short* __restrict__ B,
    const float* __restrict__ bias, unsigned short* __restrict__ C,
    float* __restrict__ Cf, unsigned short* __restrict__ vt,
    int M, int N, int K, int lda, int scaleN, float scaleVal)
{
  __shared__ unsigned short Ash[128 * 64];
  __shared__ unsigned short Bsh[128 * 64];
  const int tid = threadIdx.x;
  const int lane = tid & 63;
  const int w = tid >> 6;
  const int wr = w >> 1, wc = w & 1;
  const int l15 = lane & 15, lq = lane >> 4;
  const long bm = (long)blockIdx.y * 128;
  const long bn = (long)blockIdx.x * 128;

  f32x4 acc[4][4];
#pragma unroll
  for (int i = 0; i < 4; i++)
#pragma unroll
    for (int j = 0; j < 4; j++) acc[i][j] = f32x4{0.f, 0.f, 0.f, 0.f};

  const int rlo = lane >> 3;               // row within 8-row chunk (== row&7)
  const int sg  = (lane & 7) ^ rlo;        // pre-swizzled global segment (16B units)

  for (long k0 = 0; k0 < K; k0 += 64) {
    __syncthreads();
#pragma unroll
    for (int j = 0; j < 4; j++) {
      int c = w * 4 + j;                   // chunk 0..15, wave-uniform
      gload16(A + (bm + c * 8 + rlo) * (long)lda + k0 + sg * 8,
              (char*)Ash + c * 1024);
      gload16(B + (bn + c * 8 + rlo) * (long)K + k0 + sg * 8,
              (char*)Bsh + c * 1024);
    }
    __syncthreads();
#pragma unroll
    for (int kk = 0; kk < 2; kk++) {
      const int so = (((kk * 4 + lq) ^ (l15 & 7))) * 8;  // swizzled element offset
      bf16x8 af[4], bfr[4];
#pragma unroll
      for (int x = 0; x < 4; x++) {
        af[x]  = *reinterpret_cast<const bf16x8*>(Ash + (wr * 64 + x * 16 + l15) * 64 + so);
        bfr[x] = *reinterpret_cast<const bf16x8*>(Bsh + (wc * 64 + x * 16 + l15) * 64 + so);
      }
#pragma unroll
      for (int x = 0; x < 4; x++)
#pragma unroll
        for (int y = 0; y < 4; y++)
          acc[x][y] = __builtin_amdgcn_mfma_f32_16x16x32_bf16(af[x], bfr[y], acc[x][y], 0, 0, 0);
    }
  }

#pragma unroll
  for (int x = 0; x < 4; x++) {
    long row0 = bm + wr * 64 + x * 16 + lq * 4;
#pragma unroll
    for (int y = 0; y < 4; y++) {
      int colu = (int)bn + wc * 64 + y * 16;   // wave-uniform column base
      int col = colu + l15;
      float bs = bias[col];
      if (vt != nullptr && colu >= 2560) {
        // V part: write transposed to vt[chp][80][2048]
        int vcol = col - 2560;
        int vh = vcol / 80, vd = vcol % 80;
        int chp = ((int)(row0 >> 11)) * 16 + vh;
        int seq = (int)row0 & 2047;
        ushort4 o;
        o.x = f2bf(acc[x][y][0] + bs);
        o.y = f2bf(acc[x][y][1] + bs);
        o.z = f2bf(acc[x][y][2] + bs);
        o.w = f2bf(acc[x][y][3] + bs);
        *reinterpret_cast<ushort4*>(vt + ((size_t)chp * 80 + vd) * 2048 + seq) = o;
      } else {
        float sc = (col < scaleN) ? scaleVal : 1.0f;
        if (Cf != nullptr) {
#pragma unroll
          for (int r = 0; r < 4; r++)
            Cf[(size_t)(row0 + r) * N + col] = (acc[x][y][r] + bs) * sc;
        } else {
#pragma unroll
          for (int r = 0; r < 4; r++)
            C[(size_t)(row0 + r) * N + col] = f2bf((acc[x][y][r] + bs) * sc);
        }
      }
    }
  }
}

/* ---------------- flash attention (round-18 measured-best, byte-identical) ----------------
   Swapped-QK^T (A=K, B=Q), P packed in-register via cvt_pk, V read with the
   matching k-permutation, sum via ones-column MFMA (r19 showed the VALU
   row-sum variant spills and serializes: 176 vs 128.8 us). Occupancy pinned
   at 2 waves/SIMD regardless of reg count (r19 falsified the 128-granule
   theory; r7/r11 launch-bounds forcing spills). 128.8 us measured. */
__global__ __launch_bounds__(256, 3) void attn_kernel(
    const unsigned short* __restrict__ qkv, const unsigned short* __restrict__ vt,
    unsigned short* __restrict__ outq)
{
  __shared__ char Kbuf[10240];                  // K tile [64][80], linear
  __shared__ char Vbuf[12288];                  // V tile [80][72]

  const int tid = threadIdx.x;
  const int lane = tid & 63;
  const int w = tid >> 6;
  const int l15 = lane & 15, lq = lane >> 4;

  // XCD-aware decode: all 16 q-tiles of one (ch,head) land on one XCD
  const int b = blockIdx.x;
  const int qt = (b >> 3) & 15;
  const int chp = (b & 7) * 8 + (b >> 7);   // 0..63 = ch*16+head
  const int ch = chp >> 4;
  const int head = chp & 15;

  const size_t rs = 3840;
  const unsigned short* qbase = qkv + (size_t)(ch * CHUNK) * rs + head * HDIM;
  const char* kbase = (const char*)(qbase + 1280);
  const char* vbase = (const char*)(vt + (size_t)chp * HDIM * 2048);

  // staging geometry: per-lane 32-bit byte offsets (base kept in SGPR)
  int kgo[3]; bool kact[3];
  const int koff0 = w * 1024;
#pragma unroll
  for (int j = 0; j < 3; j++) {
    int c = w + 4 * j;
    kact[j] = (c < 10);
    int cc = kact[j] ? c : 0;
    int s = cc * 64 + lane;
    kgo[j] = (s / 10) * 7680 + (s % 10) * 16;
  }
  int vgo[3];
  const int vw = (w + 2) & 3;
#pragma unroll
  for (int j = 0; j < 3; j++) {
    int c = vw + 4 * j;
    int s2 = c * 64 + lane;
    if (s2 > 719) s2 = 719;
    int d = s2 / 9, u = s2 % 9;
    int ue = (u == 8) ? 0 : u;
    vgo[j] = d * 4096 + ue * 16;
  }

  // Q fragments in registers (same loads as always; now used as B-operands)
  const int qr0 = qt * 128 + w * 32;
  bf16x8 qa[2][2], qa2[2];
#pragma unroll
  for (int qf = 0; qf < 2; qf++) {
    const unsigned short* qrow = qbase + (size_t)(qr0 + qf * 16 + l15) * rs;
    qa[qf][0] = *reinterpret_cast<const bf16x8*>(qrow + lq * 8);
    qa[qf][1] = *reinterpret_cast<const bf16x8*>(qrow + 32 + lq * 8);
    if (lq < 2) qa2[qf] = *reinterpret_cast<const bf16x8*>(qrow + 64 + lq * 8);
    else        qa2[qf] = bf16x8{};
  }

  // ones B-fragment for the sum column (all-k ones at col 0: permutation-proof)
  bf16x8 onesb;
  {
    __bf16 o = (l15 == 0) ? (__bf16)1.0f : (__bf16)0.0f;
    onesb = bf16x8{o, o, o, o, o, o, o, o};
  }

  f32x4 acc[2][6];
#pragma unroll
  for (int qf = 0; qf < 2; qf++)
#pragma unroll
    for (int df = 0; df < 6; df++) acc[qf][df] = f32x4{0.f, 0.f, 0.f, 0.f};
  float mst[2];
  mst[0] = 16.0f; mst[1] = 16.0f;   // finite upper-bound init; per-lane q = l15

  // prologue: stage K0, V0
#pragma unroll
  for (int j = 0; j < 3; j++)
    if (kact[j]) gload16(kbase + kgo[j], Kbuf + koff0 + j * 4096);
#pragma unroll
  for (int j = 0; j < 3; j++) gload16(vbase + vgo[j], Vbuf + vw * 1024 + j * 4096);
  __syncthreads();

  for (int kt = 0; kt < CHUNK; kt += 64) {
    // swapped QK^T: sv = K-tile x Q^T -> lane holds q=l15, k=kf*16+lq*4+r
    float tmax[2] = {-1e30f, -1e30f};
    union { unsigned u[4]; bf16x8 v; } paq[2][2];   // [qf][ks], filled per-kf

    const unsigned short* Ksh = (const unsigned short*)Kbuf;
#pragma unroll
    for (int kf = 0; kf < 4; kf++) {
      const unsigned short* kr = Ksh + (kf * 16 + l15) * 80;
      bf16x8 kb0 = *reinterpret_cast<const bf16x8*>(kr + lq * 8);
      bf16x8 kb1 = *reinterpret_cast<const bf16x8*>(kr + 32 + lq * 8);
      bf16x8 kb2 = (lq < 2) ? *reinterpret_cast<const bf16x8*>(kr + 64 + lq * 8) : bf16x8{};
#pragma unroll
      for (int qf = 0; qf < 2; qf++) {
        f32x4 sv = f32x4{0.f, 0.f, 0.f, 0.f};
        sv = __builtin_amdgcn_mfma_f32_16x16x32_bf16(kb0, qa[qf][0], sv, 0, 0, 0);
        sv = __builtin_amdgcn_mfma_f32_16x16x32_bf16(kb1, qa[qf][1], sv, 0, 0, 0);
        sv = __builtin_amdgcn_mfma_f32_16x16x32_bf16(kb2, qa2[qf], sv, 0, 0, 0);
        tmax[qf] = fmaxf(tmax[qf],
                         fmaxf(fmaxf(sv[0], sv[1]), fmaxf(sv[2], sv[3])));
        float p0 = fexp2((sv[0] - mst[qf]) * L2E);
        float p1 = fexp2((sv[1] - mst[qf]) * L2E);
        float p2 = fexp2((sv[2] - mst[qf]) * L2E);
        float p3 = fexp2((sv[3] - mst[qf]) * L2E);
        paq[qf][kf >> 1].u[(kf & 1) * 2]     = cvtpk(p0, p1);
        paq[qf][kf >> 1].u[(kf & 1) * 2 + 1] = cvtpk(p2, p3);
      }
    }

    // rescale decision (post-PV application: acc_new = alpha*(acc_old + P*V))
    const bool resc = __any((tmax[0] > mst[0] + 8.0f) || (tmax[1] > mst[1] + 8.0f));
    float alpha_acc[2][4];
    if (resc) {
#pragma unroll
      for (int qf = 0; qf < 2; qf++) {
        float t = tmax[qf];
        t = fmaxf(t, __shfl_xor(t, 16, 64));
        t = fmaxf(t, __shfl_xor(t, 32, 64));
        float mnew = fmaxf(mst[qf], t);
        float a_s = fexp2((mst[qf] - mnew) * L2E);
        mst[qf] = mnew;
        // exchange alpha from s-layout (q=l15) to acc-layout (q=lq*4+r)
#pragma unroll
        for (int r = 0; r < 4; r++)
          alpha_acc[qf][r] = __shfl(a_s, lq * 4 + r, 64);
      }
    }

    __syncthreads();   // B1: all waves done reading K(t); drains V(t) loads

    // issue K(t+1); hides under PV
    if (kt + 64 < CHUNK) {
      const int ktB = (kt + 64) * 7680;
#pragma unroll
      for (int j = 0; j < 3; j++)
        if (kact[j]) gload16(kbase + kgo[j] + ktB, Kbuf + koff0 + j * 4096);
    }

    // PV (+ sum column); V read with the same k-permutation as paq
    const unsigned short* Vsh = (const unsigned short*)Vbuf;
#pragma unroll
    for (int ks = 0; ks < 2; ks++) {
#pragma unroll
      for (int df = 0; df < 5; df++) {
        const unsigned short* vp = Vsh + (df * 16 + l15) * 72 + ks * 32 + lq * 4;
        union { unsigned u[4]; bf16x8 v; } vb;
        *reinterpret_cast<uint2*>(&vb.u[0]) = *reinterpret_cast<const uint2*>(vp);
        *reinterpret_cast<uint2*>(&vb.u[2]) = *reinterpret_cast<const uint2*>(vp + 16);
#pragma unroll
        for (int qf = 0; qf < 2; qf++)
          acc[qf][df] = __builtin_amdgcn_mfma_f32_16x16x32_bf16(paq[qf][ks].v, vb.v, acc[qf][df], 0, 0, 0);
      }
#pragma unroll
      for (int qf = 0; qf < 2; qf++)
        acc[qf][5] = __builtin_amdgcn_mfma_f32_16x16x32_bf16(paq[qf][ks].v, onesb, acc[qf][5], 0, 0, 0);
    }

    // deferred rescale (rare)
    if (resc) {
#pragma unroll
      for (int qf = 0; qf < 2; qf++)
#pragma unroll
        for (int df = 0; df < 6; df++)
#pragma unroll
          for (int r = 0; r < 4; r++) acc[qf][df][r] *= alpha_acc[qf][r];
    }

    __syncthreads();   // B2: all waves done reading V(t); drains K(t+1) loads

    // issue V(t+1); hides under next tile's QK^T + softmax
    if (kt + 64 < CHUNK) {
      const int ktV = (kt + 64) * 2;
#pragma unroll
      for (int j = 0; j < 3; j++)
        gload16(vbase + vgo[j] + ktV, Vbuf + vw * 1024 + j * 4096);
    }
  }

  // epilogue: out = acc / sum (layouts unchanged: q=lq*4+r, d=df*16+l15)
  unsigned short* obase = outq + (size_t)(ch * CHUNK) * rs + head * HDIM;
#pragma unroll
  for (int qf = 0; qf < 2; qf++) {
    float inv[4];
#pragma unroll
    for (int r = 0; r < 4; r++) inv[r] = 1.0f / __shfl(acc[qf][5][r], lq * 16, 64);
#pragma unroll
    for (int df = 0; df < 5; df++) {
      int col = df * 16 + l15;
#pragma unroll
      for (int r = 0; r < 4; r++) {
        float v = acc[qf][df][r] * inv[r];
        obase[(size_t)(qr0 + qf * 16 + lq * 4 + r) * rs + col] = f2bf(v);
      }
    }
  }
}

extern "C" void kernel_launch(void* const* d_in, const int* in_sizes, int n_in,
                              void* d_out, int out_size, void* d_ws, size_t ws_size,
                              hipStream_t stream) {
  const float* hs    = (const float*)d_in[0];   // [8192][1280]
  const float* qkvw  = (const float*)d_in[2];   // [3840][1280]
  const float* qkvb  = (const float*)d_in[3];   // [3840]
  const float* projw = (const float*)d_in[4];   // [1280][1280]
  const float* projb = (const float*)d_in[5];   // [1280]

  char* ws = (char*)d_ws;
  unsigned short* hs_bf    = (unsigned short*)ws;                         // 20,971,520 B
  unsigned short* qkvw_bf  = (unsigned short*)(ws + 20971520);            //  9,830,400 B
  unsigned short* projw_bf = (unsigned short*)(ws + 20971520 + 9830400);  //  3,276,800 B
  unsigned short* qkv_bf   = (unsigned short*)(ws + 20971520 + 9830400 + 3276800); // 62,914,560 B
  // vT lives in d_out (41.9 MB fp32 buffer; scratch until proj GEMM overwrites it)
  unsigned short* vT = (unsigned short*)d_out;  // 20,971,520 B needed

  // all three fp32->bf16 converts in one launch
  cvt3_f32_bf16<<<2048, 256, 0, stream>>>(hs, hs_bf, 8192 * 1280 / 4,
                                          qkvw, qkvw_bf, 3840 * 1280 / 4,
                                          projw, projw_bf, 1280 * 1280 / 4);

  // qkv = hs @ qkv_w^T + qkv_b ; q cols pre-scaled (bf16 out); V cols -> vT transposed
  gemm_bt<<<dim3(30, 64), 256, 0, stream>>>(hs_bf, qkvw_bf, qkvb, qkv_bf, nullptr, vT,
                                            8192, 3840, 1280, 1280, 1280, QSCALE);
  // attention; output overwrites Q-columns of qkv_bf (XCD-swizzled 1-D grid)
  attn_kernel<<<dim3(1024), 256, 0, stream>>>(qkv_bf, vT, qkv_bf);
  // out = attn @ proj_w^T + proj_b (fp32 out), A has row stride 3840
  gemm_bt<<<dim3(10, 64), 256, 0, stream>>>(qkv_bf, projw_bf, projb,
                                            nullptr, (float*)d_out, nullptr,
                                            8192, 1280, 1280, 3840, 0, 1.0f);
}